// Round 5
// baseline (339.095 us; speedup 1.0000x reference)
//
#include <hip/hip_runtime.h>
#include <math.h>

#define IN_CH 256
#define HID 64
#define HEADS 8
#define F1 512   // HEADS*HID
#define OUT_CH 16
#define NEG 0.2f

typedef __attribute__((ext_vector_type(8))) short bf16x8;
typedef __attribute__((ext_vector_type(4))) float f32x4;

__device__ __forceinline__ float bflo(unsigned int v) {
  unsigned int t = v << 16; return __builtin_bit_cast(float, t);
}
__device__ __forceinline__ float bfhi(unsigned int v) {
  unsigned int t = v & 0xFFFF0000u; return __builtin_bit_cast(float, t);
}
__device__ __forceinline__ unsigned short f2bf(float f) {
  unsigned int u = __builtin_bit_cast(unsigned int, f);
  u += 0x7FFFu + ((u >> 16) & 1u);
  return (unsigned short)(u >> 16);
}
__device__ __forceinline__ void gld_lds16(const void* g, void* l) {
  __builtin_amdgcn_global_load_lds(
      (const __attribute__((address_space(1))) unsigned int*)g,
      (__attribute__((address_space(3))) unsigned int*)l, 16, 0, 0);
}

// ---------------- CSR build + prep ----------------

__global__ void init_kernel(int* counts, int* cursor, float* aad1, int n) {
  int i = blockIdx.x * blockDim.x + threadIdx.x;
  if (i < n) { counts[i] = 0; cursor[i] = 0; }
  if (i < n * HEADS * 2) aad1[i] = 0.f;
}

// count + convert x / W1T / W2T, all independent
__global__ void prep_kernel(const int* __restrict__ ei, int E, int N, int* counts,
                            const float* __restrict__ x, unsigned short* __restrict__ xb,
                            const float* __restrict__ W1, unsigned short* __restrict__ W1T,
                            const float* __restrict__ W2, unsigned short* __restrict__ W2T) {
  int idx = blockIdx.x * blockDim.x + threadIdx.x;
  int ET = E + N;
  if (idx < ET) {
    int dst = (idx < E) ? ei[E + idx] : (idx - E);
    atomicAdd(&counts[dst], 1);
  }
  size_t nx = (size_t)N * IN_CH;
  size_t stride = (size_t)gridDim.x * blockDim.x * 4;
  for (size_t i = (size_t)idx * 4; i + 3 < nx; i += stride) {
    float4 v = *(const float4*)(x + i);
    ushort4 o;
    o.x = f2bf(v.x); o.y = f2bf(v.y); o.z = f2bf(v.z); o.w = f2bf(v.w);
    *(ushort4*)(xb + i) = o;
  }
  if (idx < F1 * IN_CH) {
    int n = idx >> 8, k = idx & 255;
    W1T[idx] = f2bf(W1[k * F1 + n]);
  }
  if (idx < OUT_CH * F1) {
    int n = idx >> 9, k = idx & 511;
    W2T[idx] = f2bf(W2[k * OUT_CH + n]);
  }
}

__global__ __launch_bounds__(1024) void scan1_kernel(const int* __restrict__ counts,
                                                     int* __restrict__ offsets,
                                                     int* __restrict__ bsum, int n) {
  __shared__ int lds[1024];
  int t = threadIdx.x;
  int i = blockIdx.x * 1024 + t;
  int v = (i < n) ? counts[i] : 0;
  lds[t] = v;
  __syncthreads();
  for (int off = 1; off < 1024; off <<= 1) {
    int u = (t >= off) ? lds[t - off] : 0;
    __syncthreads();
    lds[t] += u;
    __syncthreads();
  }
  if (i < n) offsets[i] = lds[t] - v;  // block-local exclusive
  if (t == 1023) bsum[blockIdx.x] = lds[1023];
}

__global__ void scan2_kernel(const int* __restrict__ bsum, int* __restrict__ bpre,
                             int nb, int* __restrict__ offsets, int n) {
  if (threadIdx.x == 0 && blockIdx.x == 0) {
    int run = 0;
    for (int b = 0; b < nb; ++b) { bpre[b] = run; run += bsum[b]; }
    offsets[n] = run;
  }
}

__global__ __launch_bounds__(1024) void scan3_kernel(int* __restrict__ offsets,
                                                     const int* __restrict__ bpre, int n) {
  int i = blockIdx.x * 1024 + threadIdx.x;
  if (i < n) offsets[i] += bpre[blockIdx.x];
}

__global__ void fill_kernel(const int* __restrict__ ei, int E, int N,
                            const int* __restrict__ offsets, int* cursor,
                            int* __restrict__ csr_src) {
  int e = blockIdx.x * blockDim.x + threadIdx.x;
  int ET = E + N;
  if (e >= ET) return;
  int src, dst;
  if (e < E) { src = ei[e]; dst = ei[E + e]; }
  else       { src = e - E; dst = e - E; }
  int pos = atomicAdd(&cursor[dst], 1);
  csr_src[offsets[dst] + pos] = src;
}

// ---------------- GEMM1: h1 = x @ W1 (bf16 MFMA) + fused alpha1 ----------------

__global__ __launch_bounds__(256) void gemm1_mfma(const unsigned short* __restrict__ A,
                                                  const unsigned short* __restrict__ B,
                                                  const float* __restrict__ Asrc,
                                                  const float* __restrict__ Adst,
                                                  unsigned short* __restrict__ C,
                                                  float* __restrict__ aad1, int M) {
  __shared__ __align__(16) short sA[128 * 32];
  __shared__ __align__(16) short sB[128 * 32];
  int bid = blockIdx.x;
  int bm = (bid >> 2) * 128;
  int bn = (bid & 3) * 128;
  int tid = threadIdx.x;
  int w = tid >> 6, l = tid & 63;
  int wm = (w >> 1) * 64, wn = (w & 1) * 64;
  f32x4 acc[4][4];
  #pragma unroll
  for (int i = 0; i < 4; ++i)
    #pragma unroll
    for (int j = 0; j < 4; ++j) acc[i][j] = (f32x4){0.f, 0.f, 0.f, 0.f};
  int lr = l >> 2;
  int lc = (l & 3) * 8;
  for (int k0 = 0; k0 < IN_CH; k0 += 32) {
    #pragma unroll
    for (int i = 0; i < 2; ++i) {
      int ra = bm + i * 64 + w * 16 + lr;
      if (ra >= M) ra = M - 1;
      gld_lds16(A + (size_t)ra * IN_CH + k0 + lc, (char*)sA + i * 4096 + w * 1024);
      int rb = bn + i * 64 + w * 16 + lr;
      gld_lds16(B + (size_t)rb * IN_CH + k0 + lc, (char*)sB + i * 4096 + w * 1024);
    }
    __syncthreads();
    bf16x8 af[4], bfv[4];
    #pragma unroll
    for (int mi = 0; mi < 4; ++mi)
      af[mi] = *(const bf16x8*)&sA[(wm + mi * 16 + (l & 15)) * 32 + (l >> 4) * 8];
    #pragma unroll
    for (int nj = 0; nj < 4; ++nj)
      bfv[nj] = *(const bf16x8*)&sB[(wn + nj * 16 + (l & 15)) * 32 + (l >> 4) * 8];
    #pragma unroll
    for (int mi = 0; mi < 4; ++mi)
      #pragma unroll
      for (int nj = 0; nj < 4; ++nj)
        acc[mi][nj] = __builtin_amdgcn_mfma_f32_16x16x32_bf16(af[mi], bfv[nj], acc[mi][nj], 0, 0, 0);
    __syncthreads();
  }
  // C store
  #pragma unroll
  for (int mi = 0; mi < 4; ++mi) {
    #pragma unroll
    for (int j = 0; j < 4; ++j) {
      int r = bm + wm + mi * 16 + (l >> 4) * 4 + j;
      if (r < M) {
        #pragma unroll
        for (int nj = 0; nj < 4; ++nj) {
          int c = bn + wn + nj * 16 + (l & 15);
          C[(size_t)r * F1 + c] = f2bf(acc[mi][nj][j]);
        }
      }
    }
  }
  // fused alpha1 -> packed (as,ad) float2 at aad1[(r*8+head)*2 + {0,1}]
  int head = (bn + wn) >> 6;
  float asv[4], adv[4];
  #pragma unroll
  for (int nj = 0; nj < 4; ++nj) {
    int c = bn + wn + nj * 16 + (l & 15);
    asv[nj] = Asrc[c]; adv[nj] = Adst[c];
  }
  #pragma unroll
  for (int mi = 0; mi < 4; ++mi) {
    #pragma unroll
    for (int j = 0; j < 4; ++j) {
      int r = bm + wm + mi * 16 + (l >> 4) * 4 + j;
      float sv = 0.f, dv = 0.f;
      #pragma unroll
      for (int nj = 0; nj < 4; ++nj) {
        float v = acc[mi][nj][j];
        sv += v * asv[nj]; dv += v * adv[nj];
      }
      sv += __shfl_xor(sv, 1); sv += __shfl_xor(sv, 2);
      sv += __shfl_xor(sv, 4); sv += __shfl_xor(sv, 8);
      dv += __shfl_xor(dv, 1); dv += __shfl_xor(dv, 2);
      dv += __shfl_xor(dv, 4); dv += __shfl_xor(dv, 8);
      if (r < M && (l & 15) == 0) {
        atomicAdd(&aad1[(r * HEADS + head) * 2], sv);
        atomicAdd(&aad1[(r * HEADS + head) * 2 + 1], dv);
      }
    }
  }
}

// ---------------- aggr1: one wave per node, 8-deep gather pipeline ----------------

__global__ __launch_bounds__(256) void aggr1_kernel(const uint4* __restrict__ h1v,
                                                    const float2* __restrict__ aad1,
                                                    const int* __restrict__ offsets,
                                                    const int* __restrict__ csr_src,
                                                    const float* __restrict__ b1,
                                                    uint4* __restrict__ out1v, int N) {
  int tid = threadIdx.x;
  int w = tid >> 6, l = tid & 63;
  int node = blockIdx.x * 4 + w;
  if (node >= N) return;
  int beg = offsets[node], deg = offsets[node + 1] - beg;
  int he = l & 7;            // head role in p-compute (lane = e*8 + h)
  int hc = l >> 3;           // head of my channels (ch = l*8 .. l*8+7)
  float adv = aad1[node * HEADS + he].y;
  float pden = 0.f;
  float acc[8] = {};
  int e = l >> 3;
  int nfull = deg & ~7;
  // fast path: full chunks of 8, meta pipelined one chunk ahead, 8 gathers in flight
  if (nfull > 0) {
    int s_c;
    float p_c;
    {
      s_c = csr_src[beg + e];
      float2 sd = aad1[s_c * HEADS + he];
      float ev = sd.x + adv;
      ev = (ev > 0.f) ? ev : NEG * ev;
      p_c = __expf(ev);
    }
    for (int c0 = 0; c0 < nfull; c0 += 8) {
      pden += p_c;
      int ss[8]; float qq[8];
      #pragma unroll
      for (int j = 0; j < 8; ++j) {
        ss[j] = __shfl(s_c, j * 8);
        qq[j] = __shfl(p_c, j * 8 + hc);
      }
      uint4 v[8];
      #pragma unroll
      for (int j = 0; j < 8; ++j) v[j] = h1v[(size_t)ss[j] * 64 + l];
      // prefetch next chunk's meta while gathers are in flight
      if (c0 + 8 < nfull) {
        int s_n = csr_src[beg + c0 + 8 + e];
        float2 sd = aad1[s_n * HEADS + he];
        float ev = sd.x + adv;
        ev = (ev > 0.f) ? ev : NEG * ev;
        s_c = s_n;
        p_c = __expf(ev);
      }
      #pragma unroll
      for (int j = 0; j < 8; ++j) {
        float p = qq[j];
        acc[0] += p * bflo(v[j].x); acc[1] += p * bfhi(v[j].x);
        acc[2] += p * bflo(v[j].y); acc[3] += p * bfhi(v[j].y);
        acc[4] += p * bflo(v[j].z); acc[5] += p * bfhi(v[j].z);
        acc[6] += p * bflo(v[j].w); acc[7] += p * bfhi(v[j].w);
      }
    }
  }
  // tail: deg - nfull (< 8) edges, guarded
  int cnt = deg - nfull;
  if (cnt > 0) {
    int s8 = 0;
    float p8 = 0.f;
    if (e < cnt) {
      s8 = csr_src[beg + nfull + e];
      float2 sd = aad1[s8 * HEADS + he];
      float ev = sd.x + adv;
      ev = (ev > 0.f) ? ev : NEG * ev;
      p8 = __expf(ev);
      pden += p8;
    }
    for (int j = 0; j < cnt; ++j) {
      int s = __shfl(s8, j * 8);
      float p = __shfl(p8, j * 8 + hc);
      uint4 v = h1v[(size_t)s * 64 + l];
      acc[0] += p * bflo(v.x); acc[1] += p * bfhi(v.x);
      acc[2] += p * bflo(v.y); acc[3] += p * bfhi(v.y);
      acc[4] += p * bflo(v.z); acc[5] += p * bfhi(v.z);
      acc[6] += p * bflo(v.w); acc[7] += p * bfhi(v.w);
    }
  }
  // denom reduce: lanes sharing (l&7) sum -> every lane holds den for its he
  pden += __shfl_xor(pden, 8);
  pden += __shfl_xor(pden, 16);
  pden += __shfl_xor(pden, 32);
  float den = __shfl(pden, hc) + 1e-16f;
  float4 bv0 = *(const float4*)&b1[l * 8];
  float4 bv1 = *(const float4*)&b1[l * 8 + 4];
  float o[8];
  o[0] = acc[0] / den + bv0.x; o[1] = acc[1] / den + bv0.y;
  o[2] = acc[2] / den + bv0.z; o[3] = acc[3] / den + bv0.w;
  o[4] = acc[4] / den + bv1.x; o[5] = acc[5] / den + bv1.y;
  o[6] = acc[6] / den + bv1.z; o[7] = acc[7] / den + bv1.w;
  #pragma unroll
  for (int i = 0; i < 8; ++i) o[i] = (o[i] > 0.f) ? o[i] : expm1f(o[i]);
  uint4 ov;
  ov.x = (unsigned int)f2bf(o[0]) | ((unsigned int)f2bf(o[1]) << 16);
  ov.y = (unsigned int)f2bf(o[2]) | ((unsigned int)f2bf(o[3]) << 16);
  ov.z = (unsigned int)f2bf(o[4]) | ((unsigned int)f2bf(o[5]) << 16);
  ov.w = (unsigned int)f2bf(o[6]) | ((unsigned int)f2bf(o[7]) << 16);
  out1v[(size_t)node * 64 + l] = ov;
}

// ---------------- GEMM2 (MFMA) + fused alpha2 ----------------

__global__ __launch_bounds__(256) void gemm2_mfma(const unsigned short* __restrict__ A,
                                                  const unsigned short* __restrict__ W2T,
                                                  const float* __restrict__ a_src2,
                                                  const float* __restrict__ a_dst2,
                                                  float* __restrict__ t2,
                                                  float2* __restrict__ aad2, int M) {
  __shared__ __align__(16) short sA[128 * 32];   // 8 KB
  __shared__ __align__(16) short sW[16 * 512];   // 16 KB
  int tid = threadIdx.x, w = tid >> 6, l = tid & 63;
  for (int i = tid; i < 1024; i += 256) ((uint4*)sW)[i] = ((const uint4*)W2T)[i];
  int bm = blockIdx.x * 128;
  f32x4 acc[2];
  acc[0] = (f32x4){0.f, 0.f, 0.f, 0.f};
  acc[1] = (f32x4){0.f, 0.f, 0.f, 0.f};
  int lr = l >> 2, lc = (l & 3) * 8;
  for (int k0 = 0; k0 < F1; k0 += 32) {
    #pragma unroll
    for (int i = 0; i < 2; ++i) {
      int ra = bm + i * 64 + w * 16 + lr;
      if (ra >= M) ra = M - 1;
      gld_lds16(A + (size_t)ra * F1 + k0 + lc, (char*)sA + i * 4096 + w * 1024);
    }
    __syncthreads();
    bf16x8 bfv = *(const bf16x8*)&sW[(l & 15) * 512 + k0 + (l >> 4) * 8];
    #pragma unroll
    for (int mi = 0; mi < 2; ++mi) {
      bf16x8 af = *(const bf16x8*)&sA[(w * 32 + mi * 16 + (l & 15)) * 32 + (l >> 4) * 8];
      acc[mi] = __builtin_amdgcn_mfma_f32_16x16x32_bf16(af, bfv, acc[mi], 0, 0, 0);
    }
    __syncthreads();
  }
  float asv = a_src2[l & 15], adv = a_dst2[l & 15];
  #pragma unroll
  for (int mi = 0; mi < 2; ++mi) {
    #pragma unroll
    for (int j = 0; j < 4; ++j) {
      int r = bm + w * 32 + mi * 16 + (l >> 4) * 4 + j;
      float val = acc[mi][j];
      float s = val * asv, d = val * adv;
      s += __shfl_xor(s, 1); s += __shfl_xor(s, 2); s += __shfl_xor(s, 4); s += __shfl_xor(s, 8);
      d += __shfl_xor(d, 1); d += __shfl_xor(d, 2); d += __shfl_xor(d, 4); d += __shfl_xor(d, 8);
      if (r < M) {
        t2[(size_t)r * OUT_CH + (l & 15)] = val;
        if ((l & 15) == 0) aad2[r] = make_float2(s, d);
      }
    }
  }
}

// ---------------- aggr2: segment softmax (no max) + gather + log_softmax ----------------

__global__ __launch_bounds__(64) void aggr2_kernel(const float* __restrict__ t2,
                                                   const float2* __restrict__ aad2,
                                                   const int* __restrict__ offsets,
                                                   const int* __restrict__ csr_src,
                                                   const float* __restrict__ b2,
                                                   float* __restrict__ out, int N) {
  int node = blockIdx.x;
  int lane = threadIdx.x;  // 64
  int beg = offsets[node];
  int deg = offsets[node + 1] - beg;
  float ad = aad2[node].y;
  float acc = 0.f, den = 0.f;
  int eg = lane >> 4, c = lane & 15;
  for (int base = 0; base < deg; base += 4) {
    int j = base + eg;
    if (j < deg) {
      int s = csr_src[beg + j];
      float e = aad2[s].x + ad;
      e = (e > 0.f) ? e : NEG * e;
      float p = __expf(e);
      acc += p * t2[(size_t)s * OUT_CH + c];
      if (c == 0) den += p;
    }
  }
  acc += __shfl_xor(acc, 16); acc += __shfl_xor(acc, 32);
  den += __shfl_xor(den, 16); den += __shfl_xor(den, 32);
  den = __shfl(den, 0);
  float val = acc / (den + 1e-16f) + b2[c];
  float mx = val;
  #pragma unroll
  for (int off = 1; off < 16; off <<= 1) mx = fmaxf(mx, __shfl_xor(mx, off));
  float ex = __expf(val - mx);
  float se = ex;
  #pragma unroll
  for (int off = 1; off < 16; off <<= 1) se += __shfl_xor(se, off);
  float ls = val - mx - logf(se);
  if (lane < 16) out[(size_t)node * OUT_CH + lane] = ls;
}

// ---------------- launch ----------------

extern "C" void kernel_launch(void* const* d_in, const int* in_sizes, int n_in,
                              void* d_out, int out_size, void* d_ws, size_t ws_size,
                              hipStream_t stream) {
  const float* x      = (const float*)d_in[0];
  const int*   ei     = (const int*)d_in[1];
  const float* W1     = (const float*)d_in[2];
  const float* a_src1 = (const float*)d_in[3];
  const float* a_dst1 = (const float*)d_in[4];
  const float* b1     = (const float*)d_in[5];
  const float* W2     = (const float*)d_in[6];
  const float* a_src2 = (const float*)d_in[7];
  const float* a_dst2 = (const float*)d_in[8];
  const float* b2     = (const float*)d_in[9];
  float* out = (float*)d_out;

  int N = in_sizes[0] / IN_CH;
  int E = in_sizes[1] / 2;
  int ET = E + N;

  char* w = (char*)d_ws;
  auto alloc = [&](size_t bytes) -> void* {
    void* p = (void*)w;
    w += (bytes + 255) & ~(size_t)255;
    return p;
  };
  unsigned short* h1b   = (unsigned short*)alloc((size_t)N * F1 * 2);
  unsigned short* out1b = (unsigned short*)alloc((size_t)N * F1 * 2);
  unsigned short* xb    = (unsigned short*)alloc((size_t)N * IN_CH * 2);
  unsigned short* w1t   = (unsigned short*)alloc((size_t)F1 * IN_CH * 2);
  unsigned short* w2t   = (unsigned short*)alloc((size_t)OUT_CH * F1 * 2);
  float* aad1  = (float*)alloc((size_t)N * HEADS * 2 * 4);
  float* t2    = (float*)alloc((size_t)N * OUT_CH * 4);
  float* aad2  = (float*)alloc((size_t)N * 2 * 4);
  int* counts  = (int*)alloc((size_t)N * 4);
  int* offsets = (int*)alloc((size_t)(N + 1) * 4);
  int* cursor  = (int*)alloc((size_t)N * 4);
  int* bsum    = (int*)alloc(256 * 4);
  int* bpre    = (int*)alloc(256 * 4);
  int* csr_src = (int*)alloc((size_t)ET * 4);

  int nb = (N + 1023) / 1024;

  init_kernel<<<(N * HEADS * 2 + 255) / 256, 256, 0, stream>>>(counts, cursor, aad1, N);
  prep_kernel<<<(ET + 255) / 256, 256, 0, stream>>>(ei, E, N, counts, x, xb, W1, w1t, W2, w2t);
  scan1_kernel<<<nb, 1024, 0, stream>>>(counts, offsets, bsum, N);
  scan2_kernel<<<1, 64, 0, stream>>>(bsum, bpre, nb, offsets, N);
  scan3_kernel<<<nb, 1024, 0, stream>>>(offsets, bpre, N);
  fill_kernel<<<(ET + 255) / 256, 256, 0, stream>>>(ei, E, N, offsets, cursor, csr_src);

  int gx = ((N + 127) / 128) * 4;
  gemm1_mfma<<<gx, 256, 0, stream>>>(xb, w1t, a_src1, a_dst1, h1b, aad1, N);
  aggr1_kernel<<<(N + 3) / 4, 256, 0, stream>>>((const uint4*)h1b, (const float2*)aad1,
                                                offsets, csr_src, b1, (uint4*)out1b, N);
  gemm2_mfma<<<(N + 127) / 128, 256, 0, stream>>>(out1b, w2t, a_src2, a_dst2, t2,
                                                  (float2*)aad2, N);
  aggr2_kernel<<<N, 64, 0, stream>>>(t2, (const float2*)aad2, offsets, csr_src, b2, out, N);
}

// Round 6
// 333.585 us; speedup vs baseline: 1.0165x; 1.0165x over previous
//
#include <hip/hip_runtime.h>
#include <math.h>

#define IN_CH 256
#define HID 64
#define HEADS 8
#define F1 512   // HEADS*HID
#define OUT_CH 16
#define NEG 0.2f

typedef __attribute__((ext_vector_type(8))) short bf16x8;
typedef __attribute__((ext_vector_type(4))) float f32x4;

__device__ __forceinline__ float bflo(unsigned int v) {
  unsigned int t = v << 16; return __builtin_bit_cast(float, t);
}
__device__ __forceinline__ float bfhi(unsigned int v) {
  unsigned int t = v & 0xFFFF0000u; return __builtin_bit_cast(float, t);
}
__device__ __forceinline__ unsigned short f2bf(float f) {
  unsigned int u = __builtin_bit_cast(unsigned int, f);
  u += 0x7FFFu + ((u >> 16) & 1u);
  return (unsigned short)(u >> 16);
}
__device__ __forceinline__ void gld_lds16(const void* g, void* l) {
  __builtin_amdgcn_global_load_lds(
      (const __attribute__((address_space(1))) unsigned int*)g,
      (__attribute__((address_space(3))) unsigned int*)l, 16, 0, 0);
}

// ---------------- prep: count + W1 reorder-convert + W2 convert ----------------
// w1t_r layout: [kblk 0..7][kslot 0..3][n 0..511][j 0..7] bf16, k = kblk*32+kslot*8+j

__global__ void prep_kernel(const int* __restrict__ ei, int E, int N, int* counts,
                            const float* __restrict__ W1, unsigned short* __restrict__ W1R,
                            const float* __restrict__ W2, unsigned short* __restrict__ W2T) {
  int idx = blockIdx.x * blockDim.x + threadIdx.x;
  int ET = E + N;
  if (idx < ET) {
    int dst = (idx < E) ? ei[E + idx] : (idx - E);
    atomicAdd(&counts[dst], 1);
  }
  if (idx < F1 * IN_CH) {
    int n = idx >> 8, k = idx & 255;
    int r = (((k >> 5) * 4 + ((k >> 3) & 3)) * 512 + n) * 8 + (k & 7);
    W1R[r] = f2bf(W1[k * F1 + n]);
  }
  if (idx < OUT_CH * F1) {
    int n = idx >> 9, k = idx & 511;
    W2T[idx] = f2bf(W2[k * OUT_CH + n]);
  }
}

__global__ __launch_bounds__(1024) void scan1_kernel(const int* __restrict__ counts,
                                                     int* __restrict__ offsets,
                                                     int* __restrict__ bsum, int n) {
  __shared__ int lds[1024];
  int t = threadIdx.x;
  int i = blockIdx.x * 1024 + t;
  int v = (i < n) ? counts[i] : 0;
  lds[t] = v;
  __syncthreads();
  for (int off = 1; off < 1024; off <<= 1) {
    int u = (t >= off) ? lds[t - off] : 0;
    __syncthreads();
    lds[t] += u;
    __syncthreads();
  }
  if (i < n) offsets[i] = lds[t] - v;
  if (t == 1023) bsum[blockIdx.x] = lds[1023];
}

__global__ void scan2_kernel(const int* __restrict__ bsum, int* __restrict__ bpre,
                             int nb, int* __restrict__ offsets, int n) {
  if (threadIdx.x == 0 && blockIdx.x == 0) {
    int run = 0;
    for (int b = 0; b < nb; ++b) { bpre[b] = run; run += bsum[b]; }
    offsets[n] = run;
  }
}

__global__ __launch_bounds__(1024) void scan3_kernel(int* __restrict__ offsets,
                                                     const int* __restrict__ bpre, int n) {
  int i = blockIdx.x * 1024 + threadIdx.x;
  if (i < n) offsets[i] += bpre[blockIdx.x];
}

__global__ void fill_kernel(const int* __restrict__ ei, int E, int N,
                            const int* __restrict__ offsets, int* cursor,
                            int* __restrict__ csr_src) {
  int e = blockIdx.x * blockDim.x + threadIdx.x;
  int ET = E + N;
  if (e >= ET) return;
  int src, dst;
  if (e < E) { src = ei[e]; dst = ei[E + e]; }
  else       { src = e - E; dst = e - E; }
  int pos = atomicAdd(&cursor[dst], 1);
  csr_src[offsets[dst] + pos] = src;
}

// ---------------- GEMM1 v2: h1 = x @ W1, BM=64 x BN=512 (full), fused alpha1 ----------------
// A: x fp32 [M][256] read once, direct global frag loads + v_cvt_pk_bf16_f32.
// B: W1R staged to LDS [kslot][n][8] -> conflict-free ds_read_b128.
// Outputs: C = h1 bf16 [M][512]; aad1[r*8+h] = (as, ad) float2, plain stores.

__global__ __launch_bounds__(512) void gemm1_mfma(const float* __restrict__ X,
                                                  const unsigned short* __restrict__ W1R,
                                                  const float* __restrict__ Asrc,
                                                  const float* __restrict__ Adst,
                                                  unsigned short* __restrict__ C,
                                                  float2* __restrict__ aad1, int M) {
  __shared__ __align__(16) short sB[4 * 512 * 8];  // 32 KB
  int tid = threadIdx.x, w = tid >> 6, l = tid & 63;
  int wm = (w >> 2) * 32;   // 0 | 32
  int wn = (w & 3) * 128;   // 0..384
  int bm = blockIdx.x * 64;
  f32x4 acc[2][8];
  #pragma unroll
  for (int mi = 0; mi < 2; ++mi)
    #pragma unroll
    for (int nj = 0; nj < 8; ++nj) acc[mi][nj] = (f32x4){0.f, 0.f, 0.f, 0.f};
  int kslot = l >> 4;
  for (int kb = 0; kb < 8; ++kb) {
    __syncthreads();
    const unsigned short* src = W1R + kb * 16384;
    #pragma unroll
    for (int i = 0; i < 4; ++i)
      gld_lds16(src + (size_t)(i * 512 + tid) * 8, (char*)sB + (i * 512 + tid) * 16);
    // A frags direct from global fp32 (overlaps staging drain)
    bf16x8 af[2];
    int kbase = kb * 32 + kslot * 8;
    #pragma unroll
    for (int mi = 0; mi < 2; ++mi) {
      int r = bm + wm + mi * 16 + (l & 15);
      if (r >= M) r = M - 1;
      const float* ap = X + (size_t)r * IN_CH + kbase;
      float4 a0 = *(const float4*)ap;
      float4 a1 = *(const float4*)(ap + 4);
      unsigned int u0, u1, u2, u3;
      asm("v_cvt_pk_bf16_f32 %0, %1, %2" : "=v"(u0) : "v"(a0.x), "v"(a0.y));
      asm("v_cvt_pk_bf16_f32 %0, %1, %2" : "=v"(u1) : "v"(a0.z), "v"(a0.w));
      asm("v_cvt_pk_bf16_f32 %0, %1, %2" : "=v"(u2) : "v"(a1.x), "v"(a1.y));
      asm("v_cvt_pk_bf16_f32 %0, %1, %2" : "=v"(u3) : "v"(a1.z), "v"(a1.w));
      int4 pk = make_int4(u0, u1, u2, u3);
      af[mi] = __builtin_bit_cast(bf16x8, pk);
    }
    __syncthreads();
    #pragma unroll
    for (int nj = 0; nj < 8; ++nj) {
      int n = wn + nj * 16 + (l & 15);
      bf16x8 bf = *(const bf16x8*)&sB[(kslot * 512 + n) * 8];
      acc[0][nj] = __builtin_amdgcn_mfma_f32_16x16x32_bf16(af[0], bf, acc[0][nj], 0, 0, 0);
      acc[1][nj] = __builtin_amdgcn_mfma_f32_16x16x32_bf16(af[1], bf, acc[1][nj], 0, 0, 0);
    }
  }
  // epilogue: C store + alpha per-head dots (plain stores, unique writer per (r,h))
  float asv[8], adv[8];
  #pragma unroll
  for (int nj = 0; nj < 8; ++nj) {
    int c = wn + nj * 16 + (l & 15);
    asv[nj] = Asrc[c]; adv[nj] = Adst[c];
  }
  int h0 = (w & 3) * 2;
  #pragma unroll
  for (int mi = 0; mi < 2; ++mi) {
    #pragma unroll
    for (int j = 0; j < 4; ++j) {
      int r = bm + wm + mi * 16 + (l >> 4) * 4 + j;
      bool ok = (r < M);
      if (ok) {
        #pragma unroll
        for (int nj = 0; nj < 8; ++nj) {
          int c = wn + nj * 16 + (l & 15);
          C[(size_t)r * F1 + c] = f2bf(acc[mi][nj][j]);
        }
      }
      float sA = 0.f, dA = 0.f, sB2 = 0.f, dB2 = 0.f;
      #pragma unroll
      for (int nj = 0; nj < 4; ++nj) {
        float v = acc[mi][nj][j];
        sA += v * asv[nj]; dA += v * adv[nj];
      }
      #pragma unroll
      for (int nj = 4; nj < 8; ++nj) {
        float v = acc[mi][nj][j];
        sB2 += v * asv[nj]; dB2 += v * adv[nj];
      }
      #pragma unroll
      for (int off = 1; off < 16; off <<= 1) {
        sA += __shfl_xor(sA, off); dA += __shfl_xor(dA, off);
        sB2 += __shfl_xor(sB2, off); dB2 += __shfl_xor(dB2, off);
      }
      if (ok && (l & 15) == 0) {
        aad1[r * HEADS + h0]     = make_float2(sA, dA);
        aad1[r * HEADS + h0 + 1] = make_float2(sB2, dB2);
      }
    }
  }
}

// ---------------- aggr1: one wave per node (R4 schedule, float2 meta) ----------------

__global__ __launch_bounds__(256) void aggr1_kernel(const uint4* __restrict__ h1v,
                                                    const float2* __restrict__ aad1,
                                                    const int* __restrict__ offsets,
                                                    const int* __restrict__ csr_src,
                                                    const float* __restrict__ b1,
                                                    uint4* __restrict__ out1v, int N) {
  int tid = threadIdx.x;
  int w = tid >> 6, l = tid & 63;
  int node = blockIdx.x * 4 + w;
  if (node >= N) return;
  int beg = offsets[node], deg = offsets[node + 1] - beg;
  int he = l & 7;            // head role in p-compute (lane = e*8 + h)
  int hc = l >> 3;           // head of my channels
  float adv = aad1[node * HEADS + he].y;
  float pden = 0.f;
  float acc[8] = {};
  int e = l >> 3;
  for (int c0 = 0; c0 < deg; c0 += 8) {
    int cnt = min(8, deg - c0);
    int s8 = 0;
    float p8 = 0.f;
    if (e < cnt) {
      s8 = csr_src[beg + c0 + e];
      float2 sd = aad1[s8 * HEADS + he];
      float ev = sd.x + adv;
      ev = (ev > 0.f) ? ev : NEG * ev;
      p8 = __expf(ev);
      pden += p8;
    }
    for (int j = 0; j < cnt; ++j) {
      int s = __shfl(s8, j * 8);
      float p = __shfl(p8, j * 8 + hc);
      uint4 v = h1v[(size_t)s * 64 + l];
      acc[0] += p * bflo(v.x); acc[1] += p * bfhi(v.x);
      acc[2] += p * bflo(v.y); acc[3] += p * bfhi(v.y);
      acc[4] += p * bflo(v.z); acc[5] += p * bfhi(v.z);
      acc[6] += p * bflo(v.w); acc[7] += p * bfhi(v.w);
    }
  }
  pden += __shfl_xor(pden, 8);
  pden += __shfl_xor(pden, 16);
  pden += __shfl_xor(pden, 32);
  float den = __shfl(pden, hc) + 1e-16f;
  float4 bv0 = *(const float4*)&b1[l * 8];
  float4 bv1 = *(const float4*)&b1[l * 8 + 4];
  float o[8];
  o[0] = acc[0] / den + bv0.x; o[1] = acc[1] / den + bv0.y;
  o[2] = acc[2] / den + bv0.z; o[3] = acc[3] / den + bv0.w;
  o[4] = acc[4] / den + bv1.x; o[5] = acc[5] / den + bv1.y;
  o[6] = acc[6] / den + bv1.z; o[7] = acc[7] / den + bv1.w;
  #pragma unroll
  for (int i = 0; i < 8; ++i) o[i] = (o[i] > 0.f) ? o[i] : expm1f(o[i]);
  uint4 ov;
  ov.x = (unsigned int)f2bf(o[0]) | ((unsigned int)f2bf(o[1]) << 16);
  ov.y = (unsigned int)f2bf(o[2]) | ((unsigned int)f2bf(o[3]) << 16);
  ov.z = (unsigned int)f2bf(o[4]) | ((unsigned int)f2bf(o[5]) << 16);
  ov.w = (unsigned int)f2bf(o[6]) | ((unsigned int)f2bf(o[7]) << 16);
  out1v[(size_t)node * 64 + l] = ov;
}

// ---------------- GEMM2 (MFMA) + fused alpha2 ----------------

__global__ __launch_bounds__(256) void gemm2_mfma(const unsigned short* __restrict__ A,
                                                  const unsigned short* __restrict__ W2T,
                                                  const float* __restrict__ a_src2,
                                                  const float* __restrict__ a_dst2,
                                                  float* __restrict__ t2,
                                                  float2* __restrict__ aad2, int M) {
  __shared__ __align__(16) short sA[128 * 32];   // 8 KB
  __shared__ __align__(16) short sW[16 * 512];   // 16 KB
  int tid = threadIdx.x, w = tid >> 6, l = tid & 63;
  for (int i = tid; i < 1024; i += 256) ((uint4*)sW)[i] = ((const uint4*)W2T)[i];
  int bm = blockIdx.x * 128;
  f32x4 acc[2];
  acc[0] = (f32x4){0.f, 0.f, 0.f, 0.f};
  acc[1] = (f32x4){0.f, 0.f, 0.f, 0.f};
  int lr = l >> 2, lc = (l & 3) * 8;
  for (int k0 = 0; k0 < F1; k0 += 32) {
    #pragma unroll
    for (int i = 0; i < 2; ++i) {
      int ra = bm + i * 64 + w * 16 + lr;
      if (ra >= M) ra = M - 1;
      gld_lds16(A + (size_t)ra * F1 + k0 + lc, (char*)sA + i * 4096 + w * 1024);
    }
    __syncthreads();
    bf16x8 bfv = *(const bf16x8*)&sW[(l & 15) * 512 + k0 + (l >> 4) * 8];
    #pragma unroll
    for (int mi = 0; mi < 2; ++mi) {
      bf16x8 af = *(const bf16x8*)&sA[(w * 32 + mi * 16 + (l & 15)) * 32 + (l >> 4) * 8];
      acc[mi] = __builtin_amdgcn_mfma_f32_16x16x32_bf16(af, bfv, acc[mi], 0, 0, 0);
    }
    __syncthreads();
  }
  float asv = a_src2[l & 15], adv = a_dst2[l & 15];
  #pragma unroll
  for (int mi = 0; mi < 2; ++mi) {
    #pragma unroll
    for (int j = 0; j < 4; ++j) {
      int r = bm + w * 32 + mi * 16 + (l >> 4) * 4 + j;
      float val = acc[mi][j];
      float s = val * asv, d = val * adv;
      s += __shfl_xor(s, 1); s += __shfl_xor(s, 2); s += __shfl_xor(s, 4); s += __shfl_xor(s, 8);
      d += __shfl_xor(d, 1); d += __shfl_xor(d, 2); d += __shfl_xor(d, 4); d += __shfl_xor(d, 8);
      if (r < M) {
        t2[(size_t)r * OUT_CH + (l & 15)] = val;
        if ((l & 15) == 0) aad2[r] = make_float2(s, d);
      }
    }
  }
}

// ---------------- aggr2: 4 nodes/block, segment softmax + gather + log_softmax ----------------

__global__ __launch_bounds__(256) void aggr2_kernel(const float* __restrict__ t2,
                                                    const float2* __restrict__ aad2,
                                                    const int* __restrict__ offsets,
                                                    const int* __restrict__ csr_src,
                                                    const float* __restrict__ b2,
                                                    float* __restrict__ out, int N) {
  int tid = threadIdx.x;
  int node = blockIdx.x * 4 + (tid >> 6);
  int lane = tid & 63;
  if (node >= N) return;
  int beg = offsets[node];
  int deg = offsets[node + 1] - beg;
  float ad = aad2[node].y;
  float acc = 0.f, den = 0.f;
  int eg = lane >> 4, c = lane & 15;
  for (int base = 0; base < deg; base += 4) {
    int j = base + eg;
    if (j < deg) {
      int s = csr_src[beg + j];
      float e = aad2[s].x + ad;
      e = (e > 0.f) ? e : NEG * e;
      float p = __expf(e);
      acc += p * t2[(size_t)s * OUT_CH + c];
      if (c == 0) den += p;
    }
  }
  acc += __shfl_xor(acc, 16); acc += __shfl_xor(acc, 32);
  den += __shfl_xor(den, 16); den += __shfl_xor(den, 32);
  den = __shfl(den, 0);
  float val = acc / (den + 1e-16f) + b2[c];
  float mx = val;
  #pragma unroll
  for (int off = 1; off < 16; off <<= 1) mx = fmaxf(mx, __shfl_xor(mx, off));
  float ex = __expf(val - mx);
  float se = ex;
  #pragma unroll
  for (int off = 1; off < 16; off <<= 1) se += __shfl_xor(se, off);
  float ls = val - mx - logf(se);
  if (lane < 16) out[(size_t)node * OUT_CH + lane] = ls;
}

// ---------------- launch ----------------

extern "C" void kernel_launch(void* const* d_in, const int* in_sizes, int n_in,
                              void* d_out, int out_size, void* d_ws, size_t ws_size,
                              hipStream_t stream) {
  const float* x      = (const float*)d_in[0];
  const int*   ei     = (const int*)d_in[1];
  const float* W1     = (const float*)d_in[2];
  const float* a_src1 = (const float*)d_in[3];
  const float* a_dst1 = (const float*)d_in[4];
  const float* b1     = (const float*)d_in[5];
  const float* W2     = (const float*)d_in[6];
  const float* a_src2 = (const float*)d_in[7];
  const float* a_dst2 = (const float*)d_in[8];
  const float* b2     = (const float*)d_in[9];
  float* out = (float*)d_out;

  int N = in_sizes[0] / IN_CH;
  int E = in_sizes[1] / 2;
  int ET = E + N;

  char* w = (char*)d_ws;
  auto alloc = [&](size_t bytes) -> void* {
    void* p = (void*)w;
    w += (bytes + 255) & ~(size_t)255;
    return p;
  };
  unsigned short* h1b   = (unsigned short*)alloc((size_t)N * F1 * 2);
  unsigned short* out1b = (unsigned short*)alloc((size_t)N * F1 * 2);
  unsigned short* w1r   = (unsigned short*)alloc((size_t)F1 * IN_CH * 2);
  unsigned short* w2t   = (unsigned short*)alloc((size_t)OUT_CH * F1 * 2);
  float* aad1  = (float*)alloc((size_t)N * HEADS * 8);      // float2 per (r,h)
  float* t2    = (float*)alloc((size_t)N * OUT_CH * 4);
  float* aad2  = (float*)alloc((size_t)N * 8);              // float2 per r
  int* counts  = (int*)alloc((size_t)N * 2 * 4);            // counts + cursor adjacent
  int* cursor  = counts + N;
  int* offsets = (int*)alloc((size_t)(N + 1) * 4);
  int* bsum    = (int*)alloc(256 * 4);
  int* bpre    = (int*)alloc(256 * 4);
  int* csr_src = (int*)alloc((size_t)ET * 4);

  int nb = (N + 1023) / 1024;

  hipMemsetAsync(counts, 0, (size_t)N * 2 * 4, stream);
  prep_kernel<<<(ET + 255) / 256, 256, 0, stream>>>(ei, E, N, counts, W1, w1r, W2, w2t);
  scan1_kernel<<<nb, 1024, 0, stream>>>(counts, offsets, bsum, N);
  scan2_kernel<<<1, 64, 0, stream>>>(bsum, bpre, nb, offsets, N);
  scan3_kernel<<<nb, 1024, 0, stream>>>(offsets, bpre, N);
  fill_kernel<<<(ET + 255) / 256, 256, 0, stream>>>(ei, E, N, offsets, cursor, csr_src);

  gemm1_mfma<<<(N + 63) / 64, 512, 0, stream>>>(x, w1r, a_src1, a_dst1, h1b,
                                                (float2*)aad1, N);
  aggr1_kernel<<<(N + 3) / 4, 256, 0, stream>>>((const uint4*)h1b, (const float2*)aad1,
                                                offsets, csr_src, b1, (uint4*)out1b, N);
  gemm2_mfma<<<(N + 127) / 128, 256, 0, stream>>>(out1b, w2t, a_src2, a_dst2, t2,
                                                  (float2*)aad2, N);
  aggr2_kernel<<<(N + 3) / 4, 256, 0, stream>>>(t2, (const float2*)aad2, offsets, csr_src,
                                                b2, out, N);
}